// Round 10
// baseline (366.402 us; speedup 1.0000x reference)
//
#include <hip/hip_runtime.h>

typedef unsigned short u16;
typedef unsigned int u32;

constexpr int H_ = 64;
constexpr int W_ = 256;
constexpr int HW_ = H_ * W_;

typedef __bf16 bf16x8 __attribute__((ext_vector_type(8)));
typedef float f32x4 __attribute__((ext_vector_type(4)));

__device__ __forceinline__ float bf2f(u16 v) { return __uint_as_float(((u32)v) << 16); }
__device__ __forceinline__ u16 f2bf(float f) {
  u32 x = __float_as_uint(f);
  u32 r = (x + 0x7fffu + ((x >> 16) & 1u)) >> 16;
  return (u16)r;
}
__device__ __forceinline__ float lo2f(u32 p) { return __uint_as_float(p << 16); }
__device__ __forceinline__ float hi2f(u32 p) { return __uint_as_float(p & 0xffff0000u); }
__device__ __forceinline__ void unpack8(uint4 v, float* f) {
  f[0] = lo2f(v.x); f[1] = hi2f(v.x);
  f[2] = lo2f(v.y); f[3] = hi2f(v.y);
  f[4] = lo2f(v.z); f[5] = hi2f(v.z);
  f[6] = lo2f(v.w); f[7] = hi2f(v.w);
}
__device__ __forceinline__ bf16x8 as_bf16x8(uint4 v) {
  union { uint4 u; bf16x8 b; } x; x.u = v; return x.b;
}
__device__ __forceinline__ int swz(int p, int c) { return c ^ (((p >> 3) & 3) << 3); }

// ---------------- normalize all f32 inputs to a bf16 arena ----------------
constexpr int NT = 26;
constexpr int ELEMS_PER_BLK = 4096;
struct CvtArgs {
  const void* src[NT];
  u32 dst_off[NT];
  u32 n[NT];
  u32 blk_start[NT];
};

__global__ void convert_all(CvtArgs a, u16* __restrict__ dst) {
  const u32 bid = blockIdx.x;
  int ti = 0;
#pragma unroll
  for (int k = 1; k < NT; ++k) if (a.blk_start[k] <= bid) ti = k;
  const u32 e0 = (bid - a.blk_start[ti]) * ELEMS_PER_BLK;
  const u32 n = a.n[ti];
  const float* sp = (const float*)a.src[ti];
  u16* d = dst + a.dst_off[ti];
  if (e0 + ELEMS_PER_BLK <= n) {
#pragma unroll
    for (int k = 0; k < 4; ++k) {
      const u32 i = e0 + (threadIdx.x + k * 256) * 4;
      const float4 v = *(const float4*)(sp + i);
      uint2 o;
      o.x = (u32)f2bf(v.x) | ((u32)f2bf(v.y) << 16);
      o.y = (u32)f2bf(v.z) | ((u32)f2bf(v.w) << 16);
      *(uint2*)(d + i) = o;
    }
  } else {
    u32 hi = e0 + ELEMS_PER_BLK; if (hi > n) hi = n;
    for (u32 i = e0 + threadIdx.x; i < hi; i += 256) d[i] = f2bf(sp[i]);
  }
}

// ---------------- MFMA 1x1-conv GEMM with LN (K1/K2 only) ----------------
template <int CIN, int COUT>
__launch_bounds__(256)
__global__ void gemm1x1_ln(const u16* __restrict__ xA, const u16* __restrict__ xB,
                           const u16* __restrict__ w, const u16* __restrict__ bias,
                           const u16* __restrict__ lng, const u16* __restrict__ lnb,
                           float lneps, u16* __restrict__ out) {
  constexpr int POS = 64;
  constexpr int PITCH = CIN + 8;
  constexpr int MT = COUT / 64;
  __shared__ __align__(16) u16 xs[POS * PITCH];
  __shared__ float red1[256], red2[256], stm[64], str[64];
  const int t = threadIdx.x;
  const int b = blockIdx.y;
  const int pos0 = blockIdx.x * POS;

  const u16* basep = (b >= 2) ? xB : xA;
  const int bb = (b < 2) ? b : b - 2;
  const u16* xb16 = basep + (size_t)bb * CIN * HW_;

  constexpr int NLOAD = CIN * POS / 8;
  for (int idx = t; idx < NLOAD; idx += 256) {
    const int c = idx / (POS / 8);
    const int p8 = (idx % (POS / 8)) * 8;
    uint4 v = *(const uint4*)(xb16 + (size_t)c * HW_ + pos0 + p8);
    const int csw = swz(p8, c);
    u16* row = xs + p8 * PITCH + csw;
    row[0]         = (u16)v.x; row[PITCH]     = (u16)(v.x >> 16);
    row[2 * PITCH] = (u16)v.y; row[3 * PITCH] = (u16)(v.y >> 16);
    row[4 * PITCH] = (u16)v.z; row[5 * PITCH] = (u16)(v.z >> 16);
    row[6 * PITCH] = (u16)v.w; row[7 * PITCH] = (u16)(v.w >> 16);
  }
  __syncthreads();

  {  // LN over channels (CIN=128)
    const int p = t & 63, part = t >> 6;
    const int xorp = ((p >> 3) & 3) << 3;
    float s = 0.f, sq = 0.f;
#pragma unroll
    for (int k = 0; k < 32; k += 8) {
      uint4 v = *(const uint4*)(xs + p * PITCH + ((part * 32 + k) ^ xorp));
      float f[8]; unpack8(v, f);
#pragma unroll
      for (int j = 0; j < 8; ++j) { s += f[j]; sq += f[j] * f[j]; }
    }
    red1[part * 64 + p] = s; red2[part * 64 + p] = sq;
    __syncthreads();
    if (t < 64) {
      float ss = red1[t] + red1[64 + t] + red1[128 + t] + red1[192 + t];
      float qq = red2[t] + red2[64 + t] + red2[128 + t] + red2[192 + t];
      float m = ss * (1.0f / CIN);
      float var = qq * (1.0f / CIN) - m * m;
      var = var < 0.f ? 0.f : var;
      stm[t] = m; str[t] = rsqrtf(var + lneps);
    }
    __syncthreads();
    const float m = stm[p], r = str[p];
#pragma unroll
    for (int k = 0; k < 32; k += 8) {
      const int c = part * 32 + k;
      uint4 v = *(const uint4*)(xs + p * PITCH + (c ^ xorp));
      float f[8]; unpack8(v, f);
      u32 pk[4];
#pragma unroll
      for (int j = 0; j < 8; j += 2) {
        float g0 = bf2f(lng[c + j]), be0 = bf2f(lnb[c + j]);
        float g1 = bf2f(lng[c + j + 1]), be1 = bf2f(lnb[c + j + 1]);
        u16 lo = f2bf((f[j] - m) * r * g0 + be0);
        u16 hi = f2bf((f[j + 1] - m) * r * g1 + be1);
        pk[j >> 1] = (u32)lo | ((u32)hi << 16);
      }
      uint4 ov; ov.x = pk[0]; ov.y = pk[1]; ov.z = pk[2]; ov.w = pk[3];
      *(uint4*)(xs + p * PITCH + (c ^ xorp)) = ov;
    }
    __syncthreads();
  }

  const int lane = t & 63, wv = t >> 6;
  const int lo16 = lane & 15, quad = lane >> 4;
  const int orow0 = wv * MT * 16;
  const int qrow = quad * 4;

  f32x4 acc[MT][4];
#pragma unroll
  for (int mt = 0; mt < MT; ++mt) {
#pragma unroll
    for (int r = 0; r < 4; ++r) {
      const float bv = bf2f(bias[orow0 + mt * 16 + qrow + r]);
#pragma unroll
      for (int nt = 0; nt < 4; ++nt) acc[mt][nt][r] = bv;
    }
  }

  const u16* xb[4];
#pragma unroll
  for (int nt = 0; nt < 4; ++nt) {
    const int row = nt * 16 + lo16;
    xb[nt] = xs + row * PITCH + (quad * 8 ^ ((((row >> 3) & 3)) << 3));
  }
  const u16* wl = w + (size_t)(orow0 + lo16) * CIN + quad * 8;

#pragma unroll 2
  for (int kc = 0; kc < CIN / 32; ++kc) {
    const int c0 = kc * 32;
    bf16x8 bfr[4];
#pragma unroll
    for (int nt = 0; nt < 4; ++nt)
      bfr[nt] = as_bf16x8(*(const uint4*)(xb[nt] + c0));
#pragma unroll
    for (int mt = 0; mt < MT; ++mt) {
      bf16x8 afr = as_bf16x8(*(const uint4*)(wl + (size_t)mt * 16 * CIN + c0));
#pragma unroll
      for (int nt = 0; nt < 4; ++nt)
        acc[mt][nt] = __builtin_amdgcn_mfma_f32_16x16x32_bf16(afr, bfr[nt], acc[mt][nt], 0, 0, 0);
    }
  }

#pragma unroll
  for (int mt = 0; mt < MT; ++mt) {
#pragma unroll
    for (int nt = 0; nt < 4; ++nt) {
#pragma unroll
      for (int r = 0; r < 4; ++r) {
        const int o = orow0 + mt * 16 + qrow + r;
        const int p = pos0 + nt * 16 + lo16;
        out[((size_t)b * COUT + o) * HW_ + p] = f2bf(acc[mt][nt][r]);
      }
    }
  }
}

// ---------------- MFMA attention ----------------
__launch_bounds__(256)
__global__ void attn_mfma(const u16* __restrict__ qb, const u16* __restrict__ kvb,
                          u16* __restrict__ ob) {
  constexpr int PA = 40;
  constexpr int PJ = 264;
  __shared__ __align__(16) u16 kT[256 * PA];
  __shared__ __align__(16) u16 vT[32 * PJ];
  __shared__ __align__(16) u16 PlO[4 * 16 * PJ];
  const int t = threadIdx.x;
  const int h = blockIdx.x, n = blockIdx.y, b = blockIdx.z;
  const size_t qbase = ((size_t)(b * 128 + n * 32)) * HW_ + (size_t)h * W_;
  const size_t kbase = ((size_t)(b * 256 + n * 32)) * HW_ + (size_t)h * W_;
  const size_t vbase = ((size_t)(b * 256 + 128 + n * 32)) * HW_ + (size_t)h * W_;

#pragma unroll
  for (int d8 = 0; d8 < 4; ++d8) {
    u32 pk[4];
#pragma unroll
    for (int j = 0; j < 4; ++j) {
      u32 lo = kvb[kbase + (size_t)(d8 * 8 + 2 * j) * HW_ + t];
      u32 hi = kvb[kbase + (size_t)(d8 * 8 + 2 * j + 1) * HW_ + t];
      pk[j] = lo | (hi << 16);
    }
    *(uint4*)(kT + t * PA + d8 * 8) = make_uint4(pk[0], pk[1], pk[2], pk[3]);
  }
#pragma unroll
  for (int k = 0; k < 16; ++k) {
    const int idx = k * 256 + t;
    const int d = idx >> 7, p2 = (idx & 127) * 2;
    u32 v = *(const u32*)(kvb + vbase + (size_t)d * HW_ + p2);
    *(u32*)(vT + d * PJ + p2) = v;
  }
  __syncthreads();

  const int lane = t & 63, wv = t >> 6;
  const int lo16 = lane & 15, quad = lane >> 4;
  const float scale = 0.17677669529663687f;
  const float renorm = 1.0f / (1.0f + 256.0f * 1e-6f);
  const float addc = 1e-6f * renorm;
  u16* Pw = PlO + wv * 16 * PJ;

  f32x4 oacc[4][2];
  for (int ii = 0; ii < 4; ++ii) {
    const int i0 = ii * 64 + wv * 16;
    u16 qr[8];
#pragma unroll
    for (int j = 0; j < 8; ++j)
      qr[j] = qb[qbase + (size_t)(quad * 8 + j) * HW_ + i0 + lo16];
    bf16x8 qa;
#pragma unroll
    for (int j = 0; j < 8; ++j) qa[j] = *(__bf16*)&qr[j];
    f32x4 s[16];
#pragma unroll
    for (int jt = 0; jt < 16; ++jt) {
      bf16x8 kb = as_bf16x8(*(const uint4*)(kT + (jt * 16 + lo16) * PA + quad * 8));
      f32x4 z = {0.f, 0.f, 0.f, 0.f};
      s[jt] = __builtin_amdgcn_mfma_f32_16x16x32_bf16(qa, kb, z, 0, 0, 0);
    }
#pragma unroll
    for (int r = 0; r < 4; ++r) {
      float sum = 0.f;
#pragma unroll
      for (int jt = 0; jt < 16; ++jt) {
        float e = __expf(s[jt][r] * scale);
        s[jt][r] = e; sum += e;
      }
#pragma unroll
      for (int off = 1; off <= 8; off <<= 1) sum += __shfl_xor(sum, off, 64);
      const float inv2 = renorm / sum;
#pragma unroll
      for (int jt = 0; jt < 16; ++jt)
        Pw[(quad * 4 + r) * PJ + jt * 16 + lo16] = f2bf(fmaf(s[jt][r], inv2, addc));
    }
    f32x4 o0 = {0.f, 0.f, 0.f, 0.f}, o1 = {0.f, 0.f, 0.f, 0.f};
#pragma unroll
    for (int kt = 0; kt < 8; ++kt) {
      bf16x8 pa = as_bf16x8(*(const uint4*)(Pw + lo16 * PJ + kt * 32 + quad * 8));
      bf16x8 v0 = as_bf16x8(*(const uint4*)(vT + lo16 * PJ + kt * 32 + quad * 8));
      bf16x8 v1 = as_bf16x8(*(const uint4*)(vT + (16 + lo16) * PJ + kt * 32 + quad * 8));
      o0 = __builtin_amdgcn_mfma_f32_16x16x32_bf16(pa, v0, o0, 0, 0, 0);
      o1 = __builtin_amdgcn_mfma_f32_16x16x32_bf16(pa, v1, o1, 0, 0, 0);
    }
    oacc[ii][0] = o0; oacc[ii][1] = o1;
  }
  __syncthreads();
  u16* Ob = PlO;
#pragma unroll
  for (int ii = 0; ii < 4; ++ii) {
    const int i0 = ii * 64 + wv * 16;
#pragma unroll
    for (int r = 0; r < 4; ++r) {
      Ob[(i0 + quad * 4 + r) * PA + lo16] = f2bf(oacc[ii][0][r]);
      Ob[(i0 + quad * 4 + r) * PA + 16 + lo16] = f2bf(oacc[ii][1][r]);
    }
  }
  __syncthreads();
  for (int d = 0; d < 32; ++d) ob[qbase + (size_t)d * HW_ + t] = Ob[t * PA + d];
}

// ---------------- fused K4+K5: o-proj + residual -> cat1b, LN, w_in + SiLU -> yb --------
__launch_bounds__(256)
__global__ void fused_proj_ffn(const u16* __restrict__ obf,
                               const u16* __restrict__ wo, const u16* __restrict__ bo_,
                               const float* __restrict__ f1, const float* __restrict__ f2,
                               const u16* __restrict__ fng, const u16* __restrict__ fnb,
                               const u16* __restrict__ w_in, const u16* __restrict__ b_in,
                               u16* __restrict__ cat1b, u16* __restrict__ yb) {
  constexpr int PITCH = 136;
  __shared__ __align__(16) u16 xs[64 * PITCH];
  __shared__ float red1[256], red2[256], stm[64], str[64];
  const int t = threadIdx.x;
  const int b = blockIdx.y;
  const int pos0 = blockIdx.x * 64;
  const u16* xb16 = obf + (size_t)b * 128 * HW_;

  for (int idx = t; idx < 1024; idx += 256) {
    const int c = idx >> 3, p8 = (idx & 7) * 8;
    uint4 v = *(const uint4*)(xb16 + (size_t)c * HW_ + pos0 + p8);
    const int csw = swz(p8, c);
    u16* row = xs + p8 * PITCH + csw;
    row[0]         = (u16)v.x; row[PITCH]     = (u16)(v.x >> 16);
    row[2 * PITCH] = (u16)v.y; row[3 * PITCH] = (u16)(v.y >> 16);
    row[4 * PITCH] = (u16)v.z; row[5 * PITCH] = (u16)(v.z >> 16);
    row[6 * PITCH] = (u16)v.w; row[7 * PITCH] = (u16)(v.w >> 16);
  }
  __syncthreads();

  const int lane = t & 63, wv = t >> 6;
  const int lo16 = lane & 15, quad = lane >> 4, qrow = quad * 4;
  const u16* xb[4];
#pragma unroll
  for (int nt = 0; nt < 4; ++nt) {
    const int row = nt * 16 + lo16;
    xb[nt] = xs + row * PITCH + (quad * 8 ^ ((((row >> 3) & 3)) << 3));
  }

  // GEMM1: wo (128->128), MT=2
  const int orow0 = wv * 32;
  f32x4 acc1[2][4];
#pragma unroll
  for (int mt = 0; mt < 2; ++mt)
#pragma unroll
    for (int r = 0; r < 4; ++r) {
      const float bv = bf2f(bo_[orow0 + mt * 16 + qrow + r]);
#pragma unroll
      for (int nt = 0; nt < 4; ++nt) acc1[mt][nt][r] = bv;
    }
  const u16* wl1 = wo + (size_t)(orow0 + lo16) * 128 + quad * 8;
#pragma unroll
  for (int kc = 0; kc < 4; ++kc) {
    const int c0 = kc * 32;
    bf16x8 bfr[4];
#pragma unroll
    for (int nt = 0; nt < 4; ++nt) bfr[nt] = as_bf16x8(*(const uint4*)(xb[nt] + c0));
#pragma unroll
    for (int mt = 0; mt < 2; ++mt) {
      bf16x8 afr = as_bf16x8(*(const uint4*)(wl1 + (size_t)mt * 16 * 128 + c0));
#pragma unroll
      for (int nt = 0; nt < 4; ++nt)
        acc1[mt][nt] = __builtin_amdgcn_mfma_f32_16x16x32_bf16(afr, bfr[nt], acc1[mt][nt], 0, 0, 0);
    }
  }
  __syncthreads();   // all waves done reading xs

  // epilogue1: +cat1 (f32 originals), write cat1b global + xs (re-staged)
  {
    const int bl = (b < 2) ? b : b - 2;
    const float* rb = (b < 2) ? f1 : f2;
#pragma unroll
    for (int mt = 0; mt < 2; ++mt)
#pragma unroll
      for (int nt = 0; nt < 4; ++nt)
#pragma unroll
        for (int r = 0; r < 4; ++r) {
          const int o = orow0 + mt * 16 + qrow + r;
          const int p = nt * 16 + lo16;
          float v = acc1[mt][nt][r] + rb[((size_t)bl * 128 + o) * HW_ + pos0 + p];
          const u16 bv = f2bf(v);
          cat1b[((size_t)b * 128 + o) * HW_ + pos0 + p] = bv;
          xs[p * PITCH + swz(p, o)] = bv;
        }
  }
  __syncthreads();

  {  // LN (fn, eps 1e-5)
    const int p = t & 63, part = t >> 6;
    const int xorp = ((p >> 3) & 3) << 3;
    float s = 0.f, sq = 0.f;
#pragma unroll
    for (int k = 0; k < 32; k += 8) {
      uint4 v = *(const uint4*)(xs + p * PITCH + ((part * 32 + k) ^ xorp));
      float f[8]; unpack8(v, f);
#pragma unroll
      for (int j = 0; j < 8; ++j) { s += f[j]; sq += f[j] * f[j]; }
    }
    red1[part * 64 + p] = s; red2[part * 64 + p] = sq;
    __syncthreads();
    if (t < 64) {
      float ss = red1[t] + red1[64 + t] + red1[128 + t] + red1[192 + t];
      float qq = red2[t] + red2[64 + t] + red2[128 + t] + red2[192 + t];
      float m = ss * (1.0f / 128.0f);
      float var = qq * (1.0f / 128.0f) - m * m;
      var = var < 0.f ? 0.f : var;
      stm[t] = m; str[t] = rsqrtf(var + 1e-5f);
    }
    __syncthreads();
    const float m = stm[p], r = str[p];
#pragma unroll
    for (int k = 0; k < 32; k += 8) {
      const int c = part * 32 + k;
      uint4 v = *(const uint4*)(xs + p * PITCH + (c ^ xorp));
      float f[8]; unpack8(v, f);
      u32 pk[4];
#pragma unroll
      for (int j = 0; j < 8; j += 2) {
        float g0 = bf2f(fng[c + j]), be0 = bf2f(fnb[c + j]);
        float g1 = bf2f(fng[c + j + 1]), be1 = bf2f(fnb[c + j + 1]);
        u16 lo = f2bf((f[j] - m) * r * g0 + be0);
        u16 hi = f2bf((f[j + 1] - m) * r * g1 + be1);
        pk[j >> 1] = (u32)lo | ((u32)hi << 16);
      }
      uint4 ov; ov.x = pk[0]; ov.y = pk[1]; ov.z = pk[2]; ov.w = pk[3];
      *(uint4*)(xs + p * PITCH + (c ^ xorp)) = ov;
    }
    __syncthreads();
  }

  // GEMM2: w_in (128->256), MT=4, SiLU -> yb
  const int orow2 = wv * 64;
  f32x4 acc2[4][4];
#pragma unroll
  for (int mt = 0; mt < 4; ++mt)
#pragma unroll
    for (int r = 0; r < 4; ++r) {
      const float bv = bf2f(b_in[orow2 + mt * 16 + qrow + r]);
#pragma unroll
      for (int nt = 0; nt < 4; ++nt) acc2[mt][nt][r] = bv;
    }
  const u16* wl2 = w_in + (size_t)(orow2 + lo16) * 128 + quad * 8;
#pragma unroll
  for (int kc = 0; kc < 4; ++kc) {
    const int c0 = kc * 32;
    bf16x8 bfr[4];
#pragma unroll
    for (int nt = 0; nt < 4; ++nt) bfr[nt] = as_bf16x8(*(const uint4*)(xb[nt] + c0));
#pragma unroll
    for (int mt = 0; mt < 4; ++mt) {
      bf16x8 afr = as_bf16x8(*(const uint4*)(wl2 + (size_t)mt * 16 * 128 + c0));
#pragma unroll
      for (int nt = 0; nt < 4; ++nt)
        acc2[mt][nt] = __builtin_amdgcn_mfma_f32_16x16x32_bf16(afr, bfr[nt], acc2[mt][nt], 0, 0, 0);
    }
  }
#pragma unroll
  for (int mt = 0; mt < 4; ++mt)
#pragma unroll
    for (int nt = 0; nt < 4; ++nt)
#pragma unroll
      for (int r = 0; r < 4; ++r) {
        const int o = orow2 + mt * 16 + qrow + r;
        const int p = nt * 16 + lo16;
        float v = acc2[mt][nt][r];
        v = v / (1.0f + __expf(-v));
        yb[((size_t)b * 256 + o) * HW_ + pos0 + p] = f2bf(v);
      }
}

// ---------------- fused K7+K8 (R9): R5 base + conflict-free u32-pair staging ----------
// Staging rewritten (derived, 2 lanes/bank = free):
//   thread: E = ((wv&3)<<4) | ((t>>2)&15)  ch-pair 0..63;  p8 = ((t&3)+((wv>>2)<<2))*8
//   row r in [p8,p8+8): s-bits constant per thread: s32 = 4*((t>>1)&1) + 16*(t&1)
//   write u32 (ch 2E,2E+1 packed) at (u32*)sbuf + r*68 + (E ^ s32)
//   bank(k) = 4k + (e_low ^ 4(m>>1)) + 16((wv&1)^(m&1))  -> 2 lanes/bank.
// Reads use matching row-swizzle (u16): col ^ (((row>>4)&1)<<3 | ((row>>3)&1)<<5).
// Everything else identical to the proven R5 structure.
__launch_bounds__(512, 4)
__global__ void fused_pw_out(const u16* __restrict__ fbase, size_t f_stride,
                             const u16* __restrict__ w_pw, const u16* __restrict__ b_pw,
                             const u16* __restrict__ yb,
                             const u16* __restrict__ w_out, const u16* __restrict__ b_out,
                             const u16* __restrict__ cat1b, float* __restrict__ outp,
                             int b_off) {
  constexpr int SP = 136;   // stage pitch: 128 ch + 8 pad (u16); 68 u32
  constexpr int P2 = 264;   // y2 pitch
  constexpr int NCHK = 6;   // 768 / 128
  __shared__ __align__(16) u16 sbuf[2][64 * SP];   // 2 x 17408 B = 34816 B
  u16* y2 = &sbuf[0][0];                           // overlay (needs 33792 B)

  const int t = threadIdx.x;
  const int bo2 = (int)blockIdx.y + b_off;
  const int pos0 = blockIdx.x * 64;
  const u16* xf = fbase + (size_t)blockIdx.y * f_stride;

  const int lane = t & 63, wv = t >> 6;            // wv: 0..7
  const int lo16 = lane & 15, quad = lane >> 4, qrow = quad * 4;

  // staging coords: channel pair (2E, 2E+1), 8 rows starting p8_s
  const int E = ((wv & 3) << 4) | ((t >> 2) & 15);   // 0..63
  const int m_s = t & 3;
  const int p8_s = (m_s + ((wv >> 2) << 2)) * 8;     // 0..56
  const size_t g_off = pos0 + p8_s;
  const int s32 = (((m_s >> 1) & 1) << 2) | ((m_s & 1) << 4);
  const int wbase32 = p8_s * 68 + (E ^ s32);         // u32 offset

  uint4 pf0, pf1;
  // prologue: load+write chunk 0, load chunk 1
  pf0 = *(const uint4*)(xf + (size_t)(2 * E) * HW_ + g_off);
  pf1 = *(const uint4*)(xf + (size_t)(2 * E + 1) * HW_ + g_off);
  {
    u32* d = (u32*)&sbuf[0][0] + wbase32;
    d[0 * 68] = (pf0.x & 0xffffu) | (pf1.x << 16);
    d[1 * 68] = (pf0.x >> 16) | (pf1.x & 0xffff0000u);
    d[2 * 68] = (pf0.y & 0xffffu) | (pf1.y << 16);
    d[3 * 68] = (pf0.y >> 16) | (pf1.y & 0xffff0000u);
    d[4 * 68] = (pf0.z & 0xffffu) | (pf1.z << 16);
    d[5 * 68] = (pf0.z >> 16) | (pf1.z & 0xffff0000u);
    d[6 * 68] = (pf0.w & 0xffffu) | (pf1.w << 16);
    d[7 * 68] = (pf0.w >> 16) | (pf1.w & 0xffff0000u);
  }
  pf0 = *(const uint4*)(xf + (size_t)(128 + 2 * E) * HW_ + g_off);
  pf1 = *(const uint4*)(xf + (size_t)(128 + 2 * E + 1) * HW_ + g_off);

  // GEMM1 setup: w_pw (768->256), per-wave MT=2 (32 out rows), NT=4 (64 pos)
  const int orow1 = wv * 32;
  f32x4 acc[2][4];
#pragma unroll
  for (int mt = 0; mt < 2; ++mt)
#pragma unroll
    for (int r = 0; r < 4; ++r) {
      const float bv = bf2f(b_pw[orow1 + mt * 16 + qrow + r]);
#pragma unroll
      for (int nt = 0; nt < 4; ++nt) acc[mt][nt][r] = bv;
    }
  // read offsets: addr = row*SP + (quad*8 ^ (xsw&8)) + (c0 ^ (xsw&32))
  int xbase[4], xcx[4];
#pragma unroll
  for (int nt = 0; nt < 4; ++nt) {
    const int row = nt * 16 + lo16;
    const int xsw = (((row >> 4) & 1) << 3) | (((row >> 3) & 1) << 5);
    xbase[nt] = row * SP + (quad * 8 ^ (xsw & 8));
    xcx[nt] = xsw & 32;
  }
  const u16* wl1 = w_pw + (size_t)(orow1 + lo16) * 768 + quad * 8;

  __syncthreads();   // sbuf[0] ready

  for (int ch = 0; ch < NCHK; ++ch) {
    // write chunk ch+1 into the other buffer
    if (ch + 1 < NCHK) {
      u32* d = (u32*)&sbuf[(ch + 1) & 1][0] + wbase32;
      d[0 * 68] = (pf0.x & 0xffffu) | (pf1.x << 16);
      d[1 * 68] = (pf0.x >> 16) | (pf1.x & 0xffff0000u);
      d[2 * 68] = (pf0.y & 0xffffu) | (pf1.y << 16);
      d[3 * 68] = (pf0.y >> 16) | (pf1.y & 0xffff0000u);
      d[4 * 68] = (pf0.z & 0xffffu) | (pf1.z << 16);
      d[5 * 68] = (pf0.z >> 16) | (pf1.z & 0xffff0000u);
      d[6 * 68] = (pf0.w & 0xffffu) | (pf1.w << 16);
      d[7 * 68] = (pf0.w >> 16) | (pf1.w & 0xffff0000u);
    }
    // prefetch chunk ch+2 into registers (latency hides under MFMAs below)
    if (ch + 2 < NCHK) {
      pf0 = *(const uint4*)(xf + (size_t)((ch + 2) * 128 + 2 * E) * HW_ + g_off);
      pf1 = *(const uint4*)(xf + (size_t)((ch + 2) * 128 + 2 * E + 1) * HW_ + g_off);
    }
    // compute chunk ch
    const u16* xs = sbuf[ch & 1];
    const u16* wch = wl1 + ch * 128;
#pragma unroll
    for (int kc = 0; kc < 4; ++kc) {
      const int c0 = kc * 32;
      bf16x8 bfr[4];
#pragma unroll
      for (int nt = 0; nt < 4; ++nt)
        bfr[nt] = as_bf16x8(*(const uint4*)(xs + xbase[nt] + (c0 ^ xcx[nt])));
#pragma unroll
      for (int mt = 0; mt < 2; ++mt) {
        bf16x8 afr = as_bf16x8(*(const uint4*)(wch + (size_t)mt * 16 * 768 + c0));
#pragma unroll
        for (int nt = 0; nt < 4; ++nt)
          acc[mt][nt] = __builtin_amdgcn_mfma_f32_16x16x32_bf16(afr, bfr[nt], acc[mt][nt], 0, 0, 0);
      }
    }
    __syncthreads();   // chunk ch fully consumed; writes to other buffer visible
  }

  // epilogue1: SiLU + y residual -> y2[p][c] (pitch P2), overlays sbuf
#pragma unroll
  for (int mt = 0; mt < 2; ++mt)
#pragma unroll
    for (int nt = 0; nt < 4; ++nt)
#pragma unroll
      for (int r = 0; r < 4; ++r) {
        const int o = orow1 + mt * 16 + qrow + r;
        const int p = nt * 16 + lo16;
        float v = acc[mt][nt][r];
        v = v / (1.0f + __expf(-v));
        v += bf2f(yb[((size_t)bo2 * 256 + o) * HW_ + pos0 + p]);
        y2[p * P2 + swz(p, o)] = f2bf(v);
      }
  __syncthreads();

  // GEMM2: w_out (256->128), per-wave MT=1 (16 out rows)
  int x2off[4];
#pragma unroll
  for (int nt = 0; nt < 4; ++nt) {
    const int row = nt * 16 + lo16;
    x2off[nt] = row * P2 + (quad * 8 ^ ((((row >> 3) & 3)) << 3));
  }
  const int orow2 = wv * 16;
  f32x4 acc2[4];
#pragma unroll
  for (int r = 0; r < 4; ++r) {
    const float bv = bf2f(b_out[orow2 + qrow + r]);
#pragma unroll
    for (int nt = 0; nt < 4; ++nt) acc2[nt][r] = bv;
  }
  const u16* wl2 = w_out + (size_t)(orow2 + lo16) * 256 + quad * 8;
#pragma unroll
  for (int kc = 0; kc < 8; ++kc) {
    const int c0 = kc * 32;
    bf16x8 bfr[4];
#pragma unroll
    for (int nt = 0; nt < 4; ++nt) bfr[nt] = as_bf16x8(*(const uint4*)(y2 + x2off[nt] + c0));
    bf16x8 afr = as_bf16x8(*(const uint4*)(wl2 + c0));
#pragma unroll
    for (int nt = 0; nt < 4; ++nt)
      acc2[nt] = __builtin_amdgcn_mfma_f32_16x16x32_bf16(afr, bfr[nt], acc2[nt], 0, 0, 0);
  }
#pragma unroll
  for (int nt = 0; nt < 4; ++nt)
#pragma unroll
    for (int r = 0; r < 4; ++r) {
      const int o = orow2 + qrow + r;
      const int p = nt * 16 + lo16;
      const size_t gidx = ((size_t)bo2 * 128 + o) * HW_ + pos0 + p;
      outp[gidx] = acc2[nt][r] + bf2f(cat1b[gidx]);
    }
}

// ---------------- fused depthwise 3/5/7 (R5 version, proven) ----------------
__launch_bounds__(256)
__global__ void dwconv_kernel(const u16* __restrict__ yB,
                              const u16* __restrict__ w3, const u16* __restrict__ b3,
                              const u16* __restrict__ w5, const u16* __restrict__ b5,
                              const u16* __restrict__ w7, const u16* __restrict__ b7,
                              u16* __restrict__ fB) {
  constexpr int TP = 272;                       // f32 pitch; x stored at [x+4]
  __shared__ __align__(16) float tile[10 * TP]; // 10.9 KB
  __shared__ __align__(16) float wf7p[56];
  __shared__ __align__(16) float wf5p[40];
  __shared__ __align__(16) float wf3p[12];
  const int t = threadIdx.x;
  const int c = blockIdx.y;
  const int bz = blockIdx.z;
  const int h0 = blockIdx.x * 4;
  const u16* src = yB + ((size_t)bz * 256 + c) * HW_;

  if (t < 56) {
    const int rr = t >> 3, dx = t & 7;
    wf7p[t] = (dx < 7) ? bf2f(w7[c * 49 + rr * 7 + dx]) : 0.f;
  } else if (t >= 64 && t < 104) {
    const int i = t - 64, rr = i >> 3, dx = i & 7;
    wf5p[i] = (dx < 5) ? bf2f(w5[c * 25 + rr * 5 + dx]) : 0.f;
  } else if (t >= 112 && t < 124) {
    const int i = t - 112, rr = i >> 2, dx = i & 3;
    wf3p[i] = (dx < 3) ? bf2f(w3[c * 9 + rr * 3 + dx]) : 0.f;
  }

  // stage f32 tile: tile[r][x+4] = y[h0+r-3][x], zeros outside; x in [-4,260)
  for (int idx = t; idx < 10 * 132; idx += 256) {
    const int r = idx / 132, cx = idx - r * 132;
    const int gh = h0 + r - 3, gw = cx * 2 - 4;
    float v0 = 0.f, v1 = 0.f;
    if (gh >= 0 && gh < H_ && gw >= 0 && gw < W_ - 1) {
      const u32 v = *(const u32*)(src + gh * W_ + gw);
      v0 = lo2f(v); v1 = hi2f(v);
    }
    tile[r * TP + 2 * cx] = v0;
    tile[r * TP + 2 * cx + 1] = v1;
  }
  __syncthreads();

  const int hh = t >> 6;            // 0..3 output row in tile
  const int x0 = (t & 63) * 4;      // 0..252 output col (4 px/thread)
  float a3[4], a5[4], a7[4];
#pragma unroll
  for (int j = 0; j < 4; ++j) { a3[j] = 0.f; a5[j] = 0.f; a7[j] = 0.f; }

#pragma unroll 1
  for (int rr = 0; rr < 7; ++rr) {
    const float* tr = tile + (hh + rr) * TP + x0;  // g[0] = x-value (x0-4)
    f32x4 v0 = *(const f32x4*)(tr);
    f32x4 v1 = *(const f32x4*)(tr + 4);
    f32x4 v2 = *(const f32x4*)(tr + 8);
    float g[12] = {v0[0], v0[1], v0[2], v0[3], v1[0], v1[1], v1[2], v1[3],
                   v2[0], v2[1], v2[2], v2[3]};
    {
      f32x4 wa = *(const f32x4*)(wf7p + rr * 8);
      f32x4 wb = *(const f32x4*)(wf7p + rr * 8 + 4);
#pragma unroll
      for (int p = 0; p < 4; ++p) {
        float s = a7[p];
        s = fmaf(wa[0], g[p + 1], s);
        s = fmaf(wa[1], g[p + 2], s);
        s = fmaf(wa[2], g[p + 3], s);
        s = fmaf(wa[3], g[p + 4], s);
        s = fmaf(wb[0], g[p + 5], s);
        s = fmaf(wb[1], g[p + 6], s);
        s = fmaf(wb[2], g[p + 7], s);
        a7[p] = s;
      }
    }
    if (rr >= 1 && rr <= 5) {
      f32x4 wa = *(const f32x4*)(wf5p + (rr - 1) * 8);
      const float w4v = wf5p[(rr - 1) * 8 + 4];
#pragma unroll
      for (int p = 0; p < 4; ++p) {
        float s = a5[p];
        s = fmaf(wa[0], g[p + 2], s);
        s = fmaf(wa[1], g[p + 3], s);
        s = fmaf(wa[2], g[p + 4], s);
        s = fmaf(wa[3], g[p + 5], s);
        s = fmaf(w4v, g[p + 6], s);
        a5[p] = s;
      }
    }
    if (rr >= 2 && rr <= 4) {
      f32x4 wv = *(const f32x4*)(wf3p + (rr - 2) * 4);
#pragma unroll
      for (int p = 0; p < 4; ++p) {
        float s = a3[p];
        s = fmaf(wv[0], g[p + 3], s);
        s = fmaf(wv[1], g[p + 4], s);
        s = fmaf(wv[2], g[p + 5], s);
        a3[p] = s;
      }
    }
  }

  const float B3v = bf2f(b3[c]), B5v = bf2f(b5[c]), B7v = bf2f(b7[c]);
  uint2 o3, o5, o7;
  o3.x = (u32)f2bf(a3[0] + B3v) | ((u32)f2bf(a3[1] + B3v) << 16);
  o3.y = (u32)f2bf(a3[2] + B3v) | ((u32)f2bf(a3[3] + B3v) << 16);
  o5.x = (u32)f2bf(a5[0] + B5v) | ((u32)f2bf(a5[1] + B5v) << 16);
  o5.y = (u32)f2bf(a5[2] + B5v) | ((u32)f2bf(a5[3] + B5v) << 16);
  o7.x = (u32)f2bf(a7[0] + B7v) | ((u32)f2bf(a7[1] + B7v) << 16);
  o7.y = (u32)f2bf(a7[2] + B7v) | ((u32)f2bf(a7[3] + B7v) << 16);
  const size_t o0 = (size_t)bz * 768 * HW_ + (size_t)c * HW_ + (size_t)(h0 + hh) * W_ + x0;
  *(uint2*)(fB + o0) = o3;
  *(uint2*)(fB + o0 + (size_t)256 * HW_) = o5;
  *(uint2*)(fB + o0 + (size_t)512 * HW_) = o7;
}

extern "C" void kernel_launch(void* const* d_in, const int* in_sizes, int n_in,
                              void* d_out, int out_size, void* d_ws, size_t ws_size,
                              hipStream_t stream) {
  (void)out_size; (void)n_in;
  char* ws = (char*)d_ws;
  const size_t MB = 1ull << 20;

  u16* arena = (u16*)ws;
  CvtArgs ca;
  u32 off = 0, blk = 0;
  u32 aoff[NT];
  for (int i = 0; i < NT; ++i) {
    ca.src[i] = d_in[i];
    ca.n[i] = (u32)in_sizes[i];
    ca.dst_off[i] = off;
    aoff[i] = off;
    ca.blk_start[i] = blk;
    off += (ca.n[i] + 15u) & ~15u;
    blk += (ca.n[i] + ELEMS_PER_BLK - 1) / ELEMS_PER_BLK;
  }
  const u32 total_blocks = blk;

  const u16* f1c   = arena + aoff[0];
  const u16* f2c   = arena + aoff[1];
  const u16* an_g  = arena + aoff[2];
  const u16* an_b  = arena + aoff[3];
  const u16* anc_g = arena + aoff[4];
  const u16* anc_b = arena + aoff[5];
  const u16* wq    = arena + aoff[6];
  const u16* bq    = arena + aoff[7];
  const u16* wkv   = arena + aoff[8];
  const u16* bkv   = arena + aoff[9];
  const u16* wo    = arena + aoff[10];
  const u16* bo_   = arena + aoff[11];
  const u16* fn_g  = arena + aoff[12];
  const u16* fn_b  = arena + aoff[13];
  const u16* w_in  = arena + aoff[14];
  const u16* b_in  = arena + aoff[15];
  const u16* w3    = arena + aoff[16];
  const u16* b3    = arena + aoff[17];
  const u16* w5    = arena + aoff[18];
  const u16* b5    = arena + aoff[19];
  const u16* w7    = arena + aoff[20];
  const u16* b7    = arena + aoff[21];
  const u16* w_pw  = arena + aoff[22];
  const u16* b_pw  = arena + aoff[23];
  const u16* w_out = arena + aoff[24];
  const u16* b_out = arena + aoff[25];

  // layout (MB): arena[0,18) cat1b[18,34) qb[34,50) kvb[50,82) obf[82,98)
  //              yb[34,66) (overlays qb+kvb-lo after attn)
  //              fbuf: big [66,167) / small per-batch [66,92)
  u16* cat1b  = (u16*)(ws + 18 * MB);
  u16* qb     = (u16*)(ws + 34 * MB);
  u16* kvb    = (u16*)(ws + 50 * MB);
  u16* obf    = (u16*)(ws + 82 * MB);
  u16* yb     = (u16*)(ws + 34 * MB);
  u16* fbuf   = (u16*)(ws + 66 * MB);
  float* outp = (float*)d_out;
  const bool big = ws_size >= 168 * MB;

  dim3 blk256(256);
  dim3 blk512(512);
  convert_all<<<total_blocks, 256, 0, stream>>>(ca, arena);

  gemm1x1_ln<128, 128><<<dim3(HW_ / 64, 4), blk256, 0, stream>>>(
      f1c, f2c, wq, bq, an_g, an_b, 1e-6f, qb);
  gemm1x1_ln<128, 256><<<dim3(HW_ / 64, 4), blk256, 0, stream>>>(
      f2c, f1c, wkv, bkv, anc_g, anc_b, 1e-6f, kvb);
  attn_mfma<<<dim3(64, 4, 4), blk256, 0, stream>>>(qb, kvb, obf);
  fused_proj_ffn<<<dim3(HW_ / 64, 4), blk256, 0, stream>>>(
      obf, wo, bo_, (const float*)d_in[0], (const float*)d_in[1],
      fn_g, fn_b, w_in, b_in, cat1b, yb);
  if (big) {
    dwconv_kernel<<<dim3(16, 256, 4), blk256, 0, stream>>>(yb, w3, b3, w5, b5, w7, b7, fbuf);
    fused_pw_out<<<dim3(HW_ / 64, 4), blk512, 0, stream>>>(
        fbuf, (size_t)768 * HW_, w_pw, b_pw, yb, w_out, b_out, cat1b, outp, 0);
  } else {
    for (int b = 0; b < 4; ++b) {
      dwconv_kernel<<<dim3(16, 256, 1), blk256, 0, stream>>>(
          yb + (size_t)b * 256 * HW_, w3, b3, w5, b5, w7, b7, fbuf);
      fused_pw_out<<<dim3(HW_ / 64, 1), blk512, 0, stream>>>(
          fbuf, 0, w_pw, b_pw, yb, w_out, b_out, cat1b, outp, b);
    }
  }
}

// Round 11
// 362.319 us; speedup vs baseline: 1.0113x; 1.0113x over previous
//
#include <hip/hip_runtime.h>

typedef unsigned short u16;
typedef unsigned int u32;

constexpr int H_ = 64;
constexpr int W_ = 256;
constexpr int HW_ = H_ * W_;

typedef __bf16 bf16x8 __attribute__((ext_vector_type(8)));
typedef float f32x4 __attribute__((ext_vector_type(4)));

__device__ __forceinline__ float bf2f(u16 v) { return __uint_as_float(((u32)v) << 16); }
__device__ __forceinline__ u16 f2bf(float f) {
  u32 x = __float_as_uint(f);
  u32 r = (x + 0x7fffu + ((x >> 16) & 1u)) >> 16;
  return (u16)r;
}
__device__ __forceinline__ float lo2f(u32 p) { return __uint_as_float(p << 16); }
__device__ __forceinline__ float hi2f(u32 p) { return __uint_as_float(p & 0xffff0000u); }
__device__ __forceinline__ void unpack8(uint4 v, float* f) {
  f[0] = lo2f(v.x); f[1] = hi2f(v.x);
  f[2] = lo2f(v.y); f[3] = hi2f(v.y);
  f[4] = lo2f(v.z); f[5] = hi2f(v.z);
  f[6] = lo2f(v.w); f[7] = hi2f(v.w);
}
__device__ __forceinline__ bf16x8 as_bf16x8(uint4 v) {
  union { uint4 u; bf16x8 b; } x; x.u = v; return x.b;
}
__device__ __forceinline__ int swz(int p, int c) { return c ^ (((p >> 3) & 3) << 3); }

// ---------------- normalize all f32 inputs to a bf16 arena ----------------
constexpr int NT = 26;
constexpr int ELEMS_PER_BLK = 4096;
struct CvtArgs {
  const void* src[NT];
  u32 dst_off[NT];
  u32 n[NT];
  u32 blk_start[NT];
};

__global__ void convert_all(CvtArgs a, u16* __restrict__ dst) {
  const u32 bid = blockIdx.x;
  int ti = 0;
#pragma unroll
  for (int k = 1; k < NT; ++k) if (a.blk_start[k] <= bid) ti = k;
  const u32 e0 = (bid - a.blk_start[ti]) * ELEMS_PER_BLK;
  const u32 n = a.n[ti];
  const float* sp = (const float*)a.src[ti];
  u16* d = dst + a.dst_off[ti];
  if (e0 + ELEMS_PER_BLK <= n) {
#pragma unroll
    for (int k = 0; k < 4; ++k) {
      const u32 i = e0 + (threadIdx.x + k * 256) * 4;
      const float4 v = *(const float4*)(sp + i);
      uint2 o;
      o.x = (u32)f2bf(v.x) | ((u32)f2bf(v.y) << 16);
      o.y = (u32)f2bf(v.z) | ((u32)f2bf(v.w) << 16);
      *(uint2*)(d + i) = o;
    }
  } else {
    u32 hi = e0 + ELEMS_PER_BLK; if (hi > n) hi = n;
    for (u32 i = e0 + threadIdx.x; i < hi; i += 256) d[i] = f2bf(sp[i]);
  }
}

// ---------------- MFMA 1x1-conv GEMM with LN (K1/K2 only) ----------------
template <int CIN, int COUT>
__launch_bounds__(256)
__global__ void gemm1x1_ln(const u16* __restrict__ xA, const u16* __restrict__ xB,
                           const u16* __restrict__ w, const u16* __restrict__ bias,
                           const u16* __restrict__ lng, const u16* __restrict__ lnb,
                           float lneps, u16* __restrict__ out) {
  constexpr int POS = 64;
  constexpr int PITCH = CIN + 8;
  constexpr int MT = COUT / 64;
  __shared__ __align__(16) u16 xs[POS * PITCH];
  __shared__ float red1[256], red2[256], stm[64], str[64];
  const int t = threadIdx.x;
  const int b = blockIdx.y;
  const int pos0 = blockIdx.x * POS;

  const u16* basep = (b >= 2) ? xB : xA;
  const int bb = (b < 2) ? b : b - 2;
  const u16* xb16 = basep + (size_t)bb * CIN * HW_;

  constexpr int NLOAD = CIN * POS / 8;
  for (int idx = t; idx < NLOAD; idx += 256) {
    const int c = idx / (POS / 8);
    const int p8 = (idx % (POS / 8)) * 8;
    uint4 v = *(const uint4*)(xb16 + (size_t)c * HW_ + pos0 + p8);
    const int csw = swz(p8, c);
    u16* row = xs + p8 * PITCH + csw;
    row[0]         = (u16)v.x; row[PITCH]     = (u16)(v.x >> 16);
    row[2 * PITCH] = (u16)v.y; row[3 * PITCH] = (u16)(v.y >> 16);
    row[4 * PITCH] = (u16)v.z; row[5 * PITCH] = (u16)(v.z >> 16);
    row[6 * PITCH] = (u16)v.w; row[7 * PITCH] = (u16)(v.w >> 16);
  }
  __syncthreads();

  {  // LN over channels (CIN=128)
    const int p = t & 63, part = t >> 6;
    const int xorp = ((p >> 3) & 3) << 3;
    float s = 0.f, sq = 0.f;
#pragma unroll
    for (int k = 0; k < 32; k += 8) {
      uint4 v = *(const uint4*)(xs + p * PITCH + ((part * 32 + k) ^ xorp));
      float f[8]; unpack8(v, f);
#pragma unroll
      for (int j = 0; j < 8; ++j) { s += f[j]; sq += f[j] * f[j]; }
    }
    red1[part * 64 + p] = s; red2[part * 64 + p] = sq;
    __syncthreads();
    if (t < 64) {
      float ss = red1[t] + red1[64 + t] + red1[128 + t] + red1[192 + t];
      float qq = red2[t] + red2[64 + t] + red2[128 + t] + red2[192 + t];
      float m = ss * (1.0f / CIN);
      float var = qq * (1.0f / CIN) - m * m;
      var = var < 0.f ? 0.f : var;
      stm[t] = m; str[t] = rsqrtf(var + lneps);
    }
    __syncthreads();
    const float m = stm[p], r = str[p];
#pragma unroll
    for (int k = 0; k < 32; k += 8) {
      const int c = part * 32 + k;
      uint4 v = *(const uint4*)(xs + p * PITCH + (c ^ xorp));
      float f[8]; unpack8(v, f);
      u32 pk[4];
#pragma unroll
      for (int j = 0; j < 8; j += 2) {
        float g0 = bf2f(lng[c + j]), be0 = bf2f(lnb[c + j]);
        float g1 = bf2f(lng[c + j + 1]), be1 = bf2f(lnb[c + j + 1]);
        u16 lo = f2bf((f[j] - m) * r * g0 + be0);
        u16 hi = f2bf((f[j + 1] - m) * r * g1 + be1);
        pk[j >> 1] = (u32)lo | ((u32)hi << 16);
      }
      uint4 ov; ov.x = pk[0]; ov.y = pk[1]; ov.z = pk[2]; ov.w = pk[3];
      *(uint4*)(xs + p * PITCH + (c ^ xorp)) = ov;
    }
    __syncthreads();
  }

  const int lane = t & 63, wv = t >> 6;
  const int lo16 = lane & 15, quad = lane >> 4;
  const int orow0 = wv * MT * 16;
  const int qrow = quad * 4;

  f32x4 acc[MT][4];
#pragma unroll
  for (int mt = 0; mt < MT; ++mt) {
#pragma unroll
    for (int r = 0; r < 4; ++r) {
      const float bv = bf2f(bias[orow0 + mt * 16 + qrow + r]);
#pragma unroll
      for (int nt = 0; nt < 4; ++nt) acc[mt][nt][r] = bv;
    }
  }

  const u16* xb[4];
#pragma unroll
  for (int nt = 0; nt < 4; ++nt) {
    const int row = nt * 16 + lo16;
    xb[nt] = xs + row * PITCH + (quad * 8 ^ ((((row >> 3) & 3)) << 3));
  }
  const u16* wl = w + (size_t)(orow0 + lo16) * CIN + quad * 8;

#pragma unroll 2
  for (int kc = 0; kc < CIN / 32; ++kc) {
    const int c0 = kc * 32;
    bf16x8 bfr[4];
#pragma unroll
    for (int nt = 0; nt < 4; ++nt)
      bfr[nt] = as_bf16x8(*(const uint4*)(xb[nt] + c0));
#pragma unroll
    for (int mt = 0; mt < MT; ++mt) {
      bf16x8 afr = as_bf16x8(*(const uint4*)(wl + (size_t)mt * 16 * CIN + c0));
#pragma unroll
      for (int nt = 0; nt < 4; ++nt)
        acc[mt][nt] = __builtin_amdgcn_mfma_f32_16x16x32_bf16(afr, bfr[nt], acc[mt][nt], 0, 0, 0);
    }
  }

#pragma unroll
  for (int mt = 0; mt < MT; ++mt) {
#pragma unroll
    for (int nt = 0; nt < 4; ++nt) {
#pragma unroll
      for (int r = 0; r < 4; ++r) {
        const int o = orow0 + mt * 16 + qrow + r;
        const int p = pos0 + nt * 16 + lo16;
        out[((size_t)b * COUT + o) * HW_ + p] = f2bf(acc[mt][nt][r]);
      }
    }
  }
}

// ---------------- MFMA attention ----------------
__launch_bounds__(256)
__global__ void attn_mfma(const u16* __restrict__ qb, const u16* __restrict__ kvb,
                          u16* __restrict__ ob) {
  constexpr int PA = 40;
  constexpr int PJ = 264;
  __shared__ __align__(16) u16 kT[256 * PA];
  __shared__ __align__(16) u16 vT[32 * PJ];
  __shared__ __align__(16) u16 PlO[4 * 16 * PJ];
  const int t = threadIdx.x;
  const int h = blockIdx.x, n = blockIdx.y, b = blockIdx.z;
  const size_t qbase = ((size_t)(b * 128 + n * 32)) * HW_ + (size_t)h * W_;
  const size_t kbase = ((size_t)(b * 256 + n * 32)) * HW_ + (size_t)h * W_;
  const size_t vbase = ((size_t)(b * 256 + 128 + n * 32)) * HW_ + (size_t)h * W_;

#pragma unroll
  for (int d8 = 0; d8 < 4; ++d8) {
    u32 pk[4];
#pragma unroll
    for (int j = 0; j < 4; ++j) {
      u32 lo = kvb[kbase + (size_t)(d8 * 8 + 2 * j) * HW_ + t];
      u32 hi = kvb[kbase + (size_t)(d8 * 8 + 2 * j + 1) * HW_ + t];
      pk[j] = lo | (hi << 16);
    }
    *(uint4*)(kT + t * PA + d8 * 8) = make_uint4(pk[0], pk[1], pk[2], pk[3]);
  }
#pragma unroll
  for (int k = 0; k < 16; ++k) {
    const int idx = k * 256 + t;
    const int d = idx >> 7, p2 = (idx & 127) * 2;
    u32 v = *(const u32*)(kvb + vbase + (size_t)d * HW_ + p2);
    *(u32*)(vT + d * PJ + p2) = v;
  }
  __syncthreads();

  const int lane = t & 63, wv = t >> 6;
  const int lo16 = lane & 15, quad = lane >> 4;
  const float scale = 0.17677669529663687f;
  const float renorm = 1.0f / (1.0f + 256.0f * 1e-6f);
  const float addc = 1e-6f * renorm;
  u16* Pw = PlO + wv * 16 * PJ;

  f32x4 oacc[4][2];
  for (int ii = 0; ii < 4; ++ii) {
    const int i0 = ii * 64 + wv * 16;
    u16 qr[8];
#pragma unroll
    for (int j = 0; j < 8; ++j)
      qr[j] = qb[qbase + (size_t)(quad * 8 + j) * HW_ + i0 + lo16];
    bf16x8 qa;
#pragma unroll
    for (int j = 0; j < 8; ++j) qa[j] = *(__bf16*)&qr[j];
    f32x4 s[16];
#pragma unroll
    for (int jt = 0; jt < 16; ++jt) {
      bf16x8 kb = as_bf16x8(*(const uint4*)(kT + (jt * 16 + lo16) * PA + quad * 8));
      f32x4 z = {0.f, 0.f, 0.f, 0.f};
      s[jt] = __builtin_amdgcn_mfma_f32_16x16x32_bf16(qa, kb, z, 0, 0, 0);
    }
#pragma unroll
    for (int r = 0; r < 4; ++r) {
      float sum = 0.f;
#pragma unroll
      for (int jt = 0; jt < 16; ++jt) {
        float e = __expf(s[jt][r] * scale);
        s[jt][r] = e; sum += e;
      }
#pragma unroll
      for (int off = 1; off <= 8; off <<= 1) sum += __shfl_xor(sum, off, 64);
      const float inv2 = renorm / sum;
#pragma unroll
      for (int jt = 0; jt < 16; ++jt)
        Pw[(quad * 4 + r) * PJ + jt * 16 + lo16] = f2bf(fmaf(s[jt][r], inv2, addc));
    }
    f32x4 o0 = {0.f, 0.f, 0.f, 0.f}, o1 = {0.f, 0.f, 0.f, 0.f};
#pragma unroll
    for (int kt = 0; kt < 8; ++kt) {
      bf16x8 pa = as_bf16x8(*(const uint4*)(Pw + lo16 * PJ + kt * 32 + quad * 8));
      bf16x8 v0 = as_bf16x8(*(const uint4*)(vT + lo16 * PJ + kt * 32 + quad * 8));
      bf16x8 v1 = as_bf16x8(*(const uint4*)(vT + (16 + lo16) * PJ + kt * 32 + quad * 8));
      o0 = __builtin_amdgcn_mfma_f32_16x16x32_bf16(pa, v0, o0, 0, 0, 0);
      o1 = __builtin_amdgcn_mfma_f32_16x16x32_bf16(pa, v1, o1, 0, 0, 0);
    }
    oacc[ii][0] = o0; oacc[ii][1] = o1;
  }
  __syncthreads();
  u16* Ob = PlO;
#pragma unroll
  for (int ii = 0; ii < 4; ++ii) {
    const int i0 = ii * 64 + wv * 16;
#pragma unroll
    for (int r = 0; r < 4; ++r) {
      Ob[(i0 + quad * 4 + r) * PA + lo16] = f2bf(oacc[ii][0][r]);
      Ob[(i0 + quad * 4 + r) * PA + 16 + lo16] = f2bf(oacc[ii][1][r]);
    }
  }
  __syncthreads();
  for (int d = 0; d < 32; ++d) ob[qbase + (size_t)d * HW_ + t] = Ob[t * PA + d];
}

// ---------------- fused K4+K5: o-proj + residual -> cat1b, LN, w_in + SiLU -> yb --------
__launch_bounds__(256)
__global__ void fused_proj_ffn(const u16* __restrict__ obf,
                               const u16* __restrict__ wo, const u16* __restrict__ bo_,
                               const float* __restrict__ f1, const float* __restrict__ f2,
                               const u16* __restrict__ fng, const u16* __restrict__ fnb,
                               const u16* __restrict__ w_in, const u16* __restrict__ b_in,
                               u16* __restrict__ cat1b, u16* __restrict__ yb) {
  constexpr int PITCH = 136;
  __shared__ __align__(16) u16 xs[64 * PITCH];
  __shared__ float red1[256], red2[256], stm[64], str[64];
  const int t = threadIdx.x;
  const int b = blockIdx.y;
  const int pos0 = blockIdx.x * 64;
  const u16* xb16 = obf + (size_t)b * 128 * HW_;

  for (int idx = t; idx < 1024; idx += 256) {
    const int c = idx >> 3, p8 = (idx & 7) * 8;
    uint4 v = *(const uint4*)(xb16 + (size_t)c * HW_ + pos0 + p8);
    const int csw = swz(p8, c);
    u16* row = xs + p8 * PITCH + csw;
    row[0]         = (u16)v.x; row[PITCH]     = (u16)(v.x >> 16);
    row[2 * PITCH] = (u16)v.y; row[3 * PITCH] = (u16)(v.y >> 16);
    row[4 * PITCH] = (u16)v.z; row[5 * PITCH] = (u16)(v.z >> 16);
    row[6 * PITCH] = (u16)v.w; row[7 * PITCH] = (u16)(v.w >> 16);
  }
  __syncthreads();

  const int lane = t & 63, wv = t >> 6;
  const int lo16 = lane & 15, quad = lane >> 4, qrow = quad * 4;
  const u16* xb[4];
#pragma unroll
  for (int nt = 0; nt < 4; ++nt) {
    const int row = nt * 16 + lo16;
    xb[nt] = xs + row * PITCH + (quad * 8 ^ ((((row >> 3) & 3)) << 3));
  }

  // GEMM1: wo (128->128), MT=2
  const int orow0 = wv * 32;
  f32x4 acc1[2][4];
#pragma unroll
  for (int mt = 0; mt < 2; ++mt)
#pragma unroll
    for (int r = 0; r < 4; ++r) {
      const float bv = bf2f(bo_[orow0 + mt * 16 + qrow + r]);
#pragma unroll
      for (int nt = 0; nt < 4; ++nt) acc1[mt][nt][r] = bv;
    }
  const u16* wl1 = wo + (size_t)(orow0 + lo16) * 128 + quad * 8;
#pragma unroll
  for (int kc = 0; kc < 4; ++kc) {
    const int c0 = kc * 32;
    bf16x8 bfr[4];
#pragma unroll
    for (int nt = 0; nt < 4; ++nt) bfr[nt] = as_bf16x8(*(const uint4*)(xb[nt] + c0));
#pragma unroll
    for (int mt = 0; mt < 2; ++mt) {
      bf16x8 afr = as_bf16x8(*(const uint4*)(wl1 + (size_t)mt * 16 * 128 + c0));
#pragma unroll
      for (int nt = 0; nt < 4; ++nt)
        acc1[mt][nt] = __builtin_amdgcn_mfma_f32_16x16x32_bf16(afr, bfr[nt], acc1[mt][nt], 0, 0, 0);
    }
  }
  __syncthreads();   // all waves done reading xs

  // epilogue1: +cat1 (f32 originals), write cat1b global + xs (re-staged)
  {
    const int bl = (b < 2) ? b : b - 2;
    const float* rb = (b < 2) ? f1 : f2;
#pragma unroll
    for (int mt = 0; mt < 2; ++mt)
#pragma unroll
      for (int nt = 0; nt < 4; ++nt)
#pragma unroll
        for (int r = 0; r < 4; ++r) {
          const int o = orow0 + mt * 16 + qrow + r;
          const int p = nt * 16 + lo16;
          float v = acc1[mt][nt][r] + rb[((size_t)bl * 128 + o) * HW_ + pos0 + p];
          const u16 bv = f2bf(v);
          cat1b[((size_t)b * 128 + o) * HW_ + pos0 + p] = bv;
          xs[p * PITCH + swz(p, o)] = bv;
        }
  }
  __syncthreads();

  {  // LN (fn, eps 1e-5)
    const int p = t & 63, part = t >> 6;
    const int xorp = ((p >> 3) & 3) << 3;
    float s = 0.f, sq = 0.f;
#pragma unroll
    for (int k = 0; k < 32; k += 8) {
      uint4 v = *(const uint4*)(xs + p * PITCH + ((part * 32 + k) ^ xorp));
      float f[8]; unpack8(v, f);
#pragma unroll
      for (int j = 0; j < 8; ++j) { s += f[j]; sq += f[j] * f[j]; }
    }
    red1[part * 64 + p] = s; red2[part * 64 + p] = sq;
    __syncthreads();
    if (t < 64) {
      float ss = red1[t] + red1[64 + t] + red1[128 + t] + red1[192 + t];
      float qq = red2[t] + red2[64 + t] + red2[128 + t] + red2[192 + t];
      float m = ss * (1.0f / 128.0f);
      float var = qq * (1.0f / 128.0f) - m * m;
      var = var < 0.f ? 0.f : var;
      stm[t] = m; str[t] = rsqrtf(var + 1e-5f);
    }
    __syncthreads();
    const float m = stm[p], r = str[p];
#pragma unroll
    for (int k = 0; k < 32; k += 8) {
      const int c = part * 32 + k;
      uint4 v = *(const uint4*)(xs + p * PITCH + (c ^ xorp));
      float f[8]; unpack8(v, f);
      u32 pk[4];
#pragma unroll
      for (int j = 0; j < 8; j += 2) {
        float g0 = bf2f(fng[c + j]), be0 = bf2f(fnb[c + j]);
        float g1 = bf2f(fng[c + j + 1]), be1 = bf2f(fnb[c + j + 1]);
        u16 lo = f2bf((f[j] - m) * r * g0 + be0);
        u16 hi = f2bf((f[j + 1] - m) * r * g1 + be1);
        pk[j >> 1] = (u32)lo | ((u32)hi << 16);
      }
      uint4 ov; ov.x = pk[0]; ov.y = pk[1]; ov.z = pk[2]; ov.w = pk[3];
      *(uint4*)(xs + p * PITCH + (c ^ xorp)) = ov;
    }
    __syncthreads();
  }

  // GEMM2: w_in (128->256), MT=4, SiLU -> yb
  const int orow2 = wv * 64;
  f32x4 acc2[4][4];
#pragma unroll
  for (int mt = 0; mt < 4; ++mt)
#pragma unroll
    for (int r = 0; r < 4; ++r) {
      const float bv = bf2f(b_in[orow2 + mt * 16 + qrow + r]);
#pragma unroll
      for (int nt = 0; nt < 4; ++nt) acc2[mt][nt][r] = bv;
    }
  const u16* wl2 = w_in + (size_t)(orow2 + lo16) * 128 + quad * 8;
#pragma unroll
  for (int kc = 0; kc < 4; ++kc) {
    const int c0 = kc * 32;
    bf16x8 bfr[4];
#pragma unroll
    for (int nt = 0; nt < 4; ++nt) bfr[nt] = as_bf16x8(*(const uint4*)(xb[nt] + c0));
#pragma unroll
    for (int mt = 0; mt < 4; ++mt) {
      bf16x8 afr = as_bf16x8(*(const uint4*)(wl2 + (size_t)mt * 16 * 128 + c0));
#pragma unroll
      for (int nt = 0; nt < 4; ++nt)
        acc2[mt][nt] = __builtin_amdgcn_mfma_f32_16x16x32_bf16(afr, bfr[nt], acc2[mt][nt], 0, 0, 0);
    }
  }
#pragma unroll
  for (int mt = 0; mt < 4; ++mt)
#pragma unroll
    for (int nt = 0; nt < 4; ++nt)
#pragma unroll
      for (int r = 0; r < 4; ++r) {
        const int o = orow2 + mt * 16 + qrow + r;
        const int p = nt * 16 + lo16;
        float v = acc2[mt][nt][r];
        v = v / (1.0f + __expf(-v));
        yb[((size_t)b * 256 + o) * HW_ + pos0 + p] = f2bf(v);
      }
}

// ---------------- fused K7+K8 (R5-proven, best measured): w_pw+SiLU+y-res -> w_out -----
__launch_bounds__(512, 4)
__global__ void fused_pw_out(const u16* __restrict__ fbase, size_t f_stride,
                             const u16* __restrict__ w_pw, const u16* __restrict__ b_pw,
                             const u16* __restrict__ yb,
                             const u16* __restrict__ w_out, const u16* __restrict__ b_out,
                             const u16* __restrict__ cat1b, float* __restrict__ outp,
                             int b_off) {
  constexpr int SP = 136;   // stage pitch: 128 ch + 8 pad
  constexpr int P2 = 264;   // y2 pitch
  constexpr int NCHK = 6;   // 768 / 128
  __shared__ __align__(16) u16 sbuf[2][64 * SP];   // 2 x 17408 B = 34816 B
  u16* y2 = &sbuf[0][0];                           // overlay (needs 33792 B)

  const int t = threadIdx.x;
  const int bo2 = (int)blockIdx.y + b_off;
  const int pos0 = blockIdx.x * 64;
  const u16* xf = fbase + (size_t)blockIdx.y * f_stride;

  const int lane = t & 63, wv = t >> 6;            // wv: 0..7
  const int lo16 = lane & 15, quad = lane >> 4, qrow = quad * 4;

  // per-thread staging coords: 2 x uint4 per 128-channel chunk
  const int c_s0 = t >> 3;                 // 0..63
  const int c_s1 = c_s0 + 64;              // 64..127
  const int p8_s = (t & 7) * 8;
  const size_t g_off = pos0 + p8_s;

  uint4 pf0, pf1;
  // prologue: load+write chunk 0, load chunk 1
  pf0 = *(const uint4*)(xf + (size_t)c_s0 * HW_ + g_off);
  pf1 = *(const uint4*)(xf + (size_t)c_s1 * HW_ + g_off);
  {
    u16* r0 = sbuf[0] + p8_s * SP + swz(p8_s, c_s0);
    r0[0]      = (u16)pf0.x; r0[SP]     = (u16)(pf0.x >> 16);
    r0[2 * SP] = (u16)pf0.y; r0[3 * SP] = (u16)(pf0.y >> 16);
    r0[4 * SP] = (u16)pf0.z; r0[5 * SP] = (u16)(pf0.z >> 16);
    r0[6 * SP] = (u16)pf0.w; r0[7 * SP] = (u16)(pf0.w >> 16);
    u16* r1 = sbuf[0] + p8_s * SP + swz(p8_s, c_s1);
    r1[0]      = (u16)pf1.x; r1[SP]     = (u16)(pf1.x >> 16);
    r1[2 * SP] = (u16)pf1.y; r1[3 * SP] = (u16)(pf1.y >> 16);
    r1[4 * SP] = (u16)pf1.z; r1[5 * SP] = (u16)(pf1.z >> 16);
    r1[6 * SP] = (u16)pf1.w; r1[7 * SP] = (u16)(pf1.w >> 16);
  }
  pf0 = *(const uint4*)(xf + (size_t)(128 + c_s0) * HW_ + g_off);
  pf1 = *(const uint4*)(xf + (size_t)(128 + c_s1) * HW_ + g_off);

  // GEMM1 setup: w_pw (768->256), per-wave MT=2 (32 out rows), NT=4 (64 pos)
  const int orow1 = wv * 32;
  f32x4 acc[2][4];
#pragma unroll
  for (int mt = 0; mt < 2; ++mt)
#pragma unroll
    for (int r = 0; r < 4; ++r) {
      const float bv = bf2f(b_pw[orow1 + mt * 16 + qrow + r]);
#pragma unroll
      for (int nt = 0; nt < 4; ++nt) acc[mt][nt][r] = bv;
    }
  int xoff[4];
#pragma unroll
  for (int nt = 0; nt < 4; ++nt) {
    const int row = nt * 16 + lo16;
    xoff[nt] = row * SP + (quad * 8 ^ ((((row >> 3) & 3)) << 3));
  }
  const u16* wl1 = w_pw + (size_t)(orow1 + lo16) * 768 + quad * 8;

  __syncthreads();   // sbuf[0] ready

  for (int ch = 0; ch < NCHK; ++ch) {
    // write chunk ch+1 into the other buffer (its last readers synced at end of ch-1)
    if (ch + 1 < NCHK) {
      u16* dst = sbuf[(ch + 1) & 1];
      u16* r0 = dst + p8_s * SP + swz(p8_s, c_s0);
      r0[0]      = (u16)pf0.x; r0[SP]     = (u16)(pf0.x >> 16);
      r0[2 * SP] = (u16)pf0.y; r0[3 * SP] = (u16)(pf0.y >> 16);
      r0[4 * SP] = (u16)pf0.z; r0[5 * SP] = (u16)(pf0.z >> 16);
      r0[6 * SP] = (u16)pf0.w; r0[7 * SP] = (u16)(pf0.w >> 16);
      u16* r1 = dst + p8_s * SP + swz(p8_s, c_s1);
      r1[0]      = (u16)pf1.x; r1[SP]     = (u16)(pf1.x >> 16);
      r1[2 * SP] = (u16)pf1.y; r1[3 * SP] = (u16)(pf1.y >> 16);
      r1[4 * SP] = (u16)pf1.z; r1[5 * SP] = (u16)(pf1.z >> 16);
      r1[6 * SP] = (u16)pf1.w; r1[7 * SP] = (u16)(pf1.w >> 16);
    }
    // prefetch chunk ch+2 into registers (latency hides under MFMAs below)
    if (ch + 2 < NCHK) {
      pf0 = *(const uint4*)(xf + (size_t)((ch + 2) * 128 + c_s0) * HW_ + g_off);
      pf1 = *(const uint4*)(xf + (size_t)((ch + 2) * 128 + c_s1) * HW_ + g_off);
    }
    // compute chunk ch
    const u16* xs = sbuf[ch & 1];
    const u16* wch = wl1 + ch * 128;
#pragma unroll
    for (int kc = 0; kc < 4; ++kc) {
      const int c0 = kc * 32;
      bf16x8 bfr[4];
#pragma unroll
      for (int nt = 0; nt < 4; ++nt)
        bfr[nt] = as_bf16x8(*(const uint4*)(xs + xoff[nt] + c0));
#pragma unroll
      for (int mt = 0; mt < 2; ++mt) {
        bf16x8 afr = as_bf16x8(*(const uint4*)(wch + (size_t)mt * 16 * 768 + c0));
#pragma unroll
        for (int nt = 0; nt < 4; ++nt)
          acc[mt][nt] = __builtin_amdgcn_mfma_f32_16x16x32_bf16(afr, bfr[nt], acc[mt][nt], 0, 0, 0);
      }
    }
    __syncthreads();   // chunk ch fully consumed; writes to other buffer visible
  }

  // epilogue1: SiLU + y residual -> y2[p][c] (pitch P2), overlays sbuf
#pragma unroll
  for (int mt = 0; mt < 2; ++mt)
#pragma unroll
    for (int nt = 0; nt < 4; ++nt)
#pragma unroll
      for (int r = 0; r < 4; ++r) {
        const int o = orow1 + mt * 16 + qrow + r;
        const int p = nt * 16 + lo16;
        float v = acc[mt][nt][r];
        v = v / (1.0f + __expf(-v));
        v += bf2f(yb[((size_t)bo2 * 256 + o) * HW_ + pos0 + p]);
        y2[p * P2 + swz(p, o)] = f2bf(v);
      }
  __syncthreads();

  // GEMM2: w_out (256->128), per-wave MT=1 (16 out rows)
  int x2off[4];
#pragma unroll
  for (int nt = 0; nt < 4; ++nt) {
    const int row = nt * 16 + lo16;
    x2off[nt] = row * P2 + (quad * 8 ^ ((((row >> 3) & 3)) << 3));
  }
  const int orow2 = wv * 16;
  f32x4 acc2[4];
#pragma unroll
  for (int r = 0; r < 4; ++r) {
    const float bv = bf2f(b_out[orow2 + qrow + r]);
#pragma unroll
    for (int nt = 0; nt < 4; ++nt) acc2[nt][r] = bv;
  }
  const u16* wl2 = w_out + (size_t)(orow2 + lo16) * 256 + quad * 8;
#pragma unroll
  for (int kc = 0; kc < 8; ++kc) {
    const int c0 = kc * 32;
    bf16x8 bfr[4];
#pragma unroll
    for (int nt = 0; nt < 4; ++nt) bfr[nt] = as_bf16x8(*(const uint4*)(y2 + x2off[nt] + c0));
    bf16x8 afr = as_bf16x8(*(const uint4*)(wl2 + c0));
#pragma unroll
    for (int nt = 0; nt < 4; ++nt)
      acc2[nt] = __builtin_amdgcn_mfma_f32_16x16x32_bf16(afr, bfr[nt], acc2[nt], 0, 0, 0);
  }
#pragma unroll
  for (int nt = 0; nt < 4; ++nt)
#pragma unroll
    for (int r = 0; r < 4; ++r) {
      const int o = orow2 + qrow + r;
      const int p = nt * 16 + lo16;
      const size_t gidx = ((size_t)bo2 * 128 + o) * HW_ + pos0 + p;
      outp[gidx] = acc2[nt][r] + bf2f(cat1b[gidx]);
    }
}

// ---------------- fused depthwise 3/5/7 (R5 version, proven) ----------------
__launch_bounds__(256)
__global__ void dwconv_kernel(const u16* __restrict__ yB,
                              const u16* __restrict__ w3, const u16* __restrict__ b3,
                              const u16* __restrict__ w5, const u16* __restrict__ b5,
                              const u16* __restrict__ w7, const u16* __restrict__ b7,
                              u16* __restrict__ fB) {
  constexpr int TP = 272;                       // f32 pitch; x stored at [x+4]
  __shared__ __align__(16) float tile[10 * TP]; // 10.9 KB
  __shared__ __align__(16) float wf7p[56];
  __shared__ __align__(16) float wf5p[40];
  __shared__ __align__(16) float wf3p[12];
  const int t = threadIdx.x;
  const int c = blockIdx.y;
  const int bz = blockIdx.z;
  const int h0 = blockIdx.x * 4;
  const u16* src = yB + ((size_t)bz * 256 + c) * HW_;

  if (t < 56) {
    const int rr = t >> 3, dx = t & 7;
    wf7p[t] = (dx < 7) ? bf2f(w7[c * 49 + rr * 7 + dx]) : 0.f;
  } else if (t >= 64 && t < 104) {
    const int i = t - 64, rr = i >> 3, dx = i & 7;
    wf5p[i] = (dx < 5) ? bf2f(w5[c * 25 + rr * 5 + dx]) : 0.f;
  } else if (t >= 112 && t < 124) {
    const int i = t - 112, rr = i >> 2, dx = i & 3;
    wf3p[i] = (dx < 3) ? bf2f(w3[c * 9 + rr * 3 + dx]) : 0.f;
  }

  // stage f32 tile: tile[r][x+4] = y[h0+r-3][x], zeros outside; x in [-4,260)
  for (int idx = t; idx < 10 * 132; idx += 256) {
    const int r = idx / 132, cx = idx - r * 132;
    const int gh = h0 + r - 3, gw = cx * 2 - 4;
    float v0 = 0.f, v1 = 0.f;
    if (gh >= 0 && gh < H_ && gw >= 0 && gw < W_ - 1) {
      const u32 v = *(const u32*)(src + gh * W_ + gw);
      v0 = lo2f(v); v1 = hi2f(v);
    }
    tile[r * TP + 2 * cx] = v0;
    tile[r * TP + 2 * cx + 1] = v1;
  }
  __syncthreads();

  const int hh = t >> 6;            // 0..3 output row in tile
  const int x0 = (t & 63) * 4;      // 0..252 output col (4 px/thread)
  float a3[4], a5[4], a7[4];
#pragma unroll
  for (int j = 0; j < 4; ++j) { a3[j] = 0.f; a5[j] = 0.f; a7[j] = 0.f; }

#pragma unroll 1
  for (int rr = 0; rr < 7; ++rr) {
    const float* tr = tile + (hh + rr) * TP + x0;  // g[0] = x-value (x0-4)
    f32x4 v0 = *(const f32x4*)(tr);
    f32x4 v1 = *(const f32x4*)(tr + 4);
    f32x4 v2 = *(const f32x4*)(tr + 8);
    float g[12] = {v0[0], v0[1], v0[2], v0[3], v1[0], v1[1], v1[2], v1[3],
                   v2[0], v2[1], v2[2], v2[3]};
    {
      f32x4 wa = *(const f32x4*)(wf7p + rr * 8);
      f32x4 wb = *(const f32x4*)(wf7p + rr * 8 + 4);
#pragma unroll
      for (int p = 0; p < 4; ++p) {
        float s = a7[p];
        s = fmaf(wa[0], g[p + 1], s);
        s = fmaf(wa[1], g[p + 2], s);
        s = fmaf(wa[2], g[p + 3], s);
        s = fmaf(wa[3], g[p + 4], s);
        s = fmaf(wb[0], g[p + 5], s);
        s = fmaf(wb[1], g[p + 6], s);
        s = fmaf(wb[2], g[p + 7], s);
        a7[p] = s;
      }
    }
    if (rr >= 1 && rr <= 5) {
      f32x4 wa = *(const f32x4*)(wf5p + (rr - 1) * 8);
      const float w4v = wf5p[(rr - 1) * 8 + 4];
#pragma unroll
      for (int p = 0; p < 4; ++p) {
        float s = a5[p];
        s = fmaf(wa[0], g[p + 2], s);
        s = fmaf(wa[1], g[p + 3], s);
        s = fmaf(wa[2], g[p + 4], s);
        s = fmaf(wa[3], g[p + 5], s);
        s = fmaf(w4v, g[p + 6], s);
        a5[p] = s;
      }
    }
    if (rr >= 2 && rr <= 4) {
      f32x4 wv = *(const f32x4*)(wf3p + (rr - 2) * 4);
#pragma unroll
      for (int p = 0; p < 4; ++p) {
        float s = a3[p];
        s = fmaf(wv[0], g[p + 3], s);
        s = fmaf(wv[1], g[p + 4], s);
        s = fmaf(wv[2], g[p + 5], s);
        a3[p] = s;
      }
    }
  }

  const float B3v = bf2f(b3[c]), B5v = bf2f(b5[c]), B7v = bf2f(b7[c]);
  uint2 o3, o5, o7;
  o3.x = (u32)f2bf(a3[0] + B3v) | ((u32)f2bf(a3[1] + B3v) << 16);
  o3.y = (u32)f2bf(a3[2] + B3v) | ((u32)f2bf(a3[3] + B3v) << 16);
  o5.x = (u32)f2bf(a5[0] + B5v) | ((u32)f2bf(a5[1] + B5v) << 16);
  o5.y = (u32)f2bf(a5[2] + B5v) | ((u32)f2bf(a5[3] + B5v) << 16);
  o7.x = (u32)f2bf(a7[0] + B7v) | ((u32)f2bf(a7[1] + B7v) << 16);
  o7.y = (u32)f2bf(a7[2] + B7v) | ((u32)f2bf(a7[3] + B7v) << 16);
  const size_t o0 = (size_t)bz * 768 * HW_ + (size_t)c * HW_ + (size_t)(h0 + hh) * W_ + x0;
  *(uint2*)(fB + o0) = o3;
  *(uint2*)(fB + o0 + (size_t)256 * HW_) = o5;
  *(uint2*)(fB + o0 + (size_t)512 * HW_) = o7;
}

extern "C" void kernel_launch(void* const* d_in, const int* in_sizes, int n_in,
                              void* d_out, int out_size, void* d_ws, size_t ws_size,
                              hipStream_t stream) {
  (void)out_size; (void)n_in;
  char* ws = (char*)d_ws;
  const size_t MB = 1ull << 20;

  u16* arena = (u16*)ws;
  CvtArgs ca;
  u32 off = 0, blk = 0;
  u32 aoff[NT];
  for (int i = 0; i < NT; ++i) {
    ca.src[i] = d_in[i];
    ca.n[i] = (u32)in_sizes[i];
    ca.dst_off[i] = off;
    aoff[i] = off;
    ca.blk_start[i] = blk;
    off += (ca.n[i] + 15u) & ~15u;
    blk += (ca.n[i] + ELEMS_PER_BLK - 1) / ELEMS_PER_BLK;
  }
  const u32 total_blocks = blk;

  const u16* f1c   = arena + aoff[0];
  const u16* f2c   = arena + aoff[1];
  const u16* an_g  = arena + aoff[2];
  const u16* an_b  = arena + aoff[3];
  const u16* anc_g = arena + aoff[4];
  const u16* anc_b = arena + aoff[5];
  const u16* wq    = arena + aoff[6];
  const u16* bq    = arena + aoff[7];
  const u16* wkv   = arena + aoff[8];
  const u16* bkv   = arena + aoff[9];
  const u16* wo    = arena + aoff[10];
  const u16* bo_   = arena + aoff[11];
  const u16* fn_g  = arena + aoff[12];
  const u16* fn_b  = arena + aoff[13];
  const u16* w_in  = arena + aoff[14];
  const u16* b_in  = arena + aoff[15];
  const u16* w3    = arena + aoff[16];
  const u16* b3    = arena + aoff[17];
  const u16* w5    = arena + aoff[18];
  const u16* b5    = arena + aoff[19];
  const u16* w7    = arena + aoff[20];
  const u16* b7    = arena + aoff[21];
  const u16* w_pw  = arena + aoff[22];
  const u16* b_pw  = arena + aoff[23];
  const u16* w_out = arena + aoff[24];
  const u16* b_out = arena + aoff[25];

  // layout (MB): arena[0,18) cat1b[18,34) qb[34,50) kvb[50,82) obf[82,98)
  //              yb[34,66) (overlays qb+kvb-lo after attn)
  //              fbuf: big [66,167) / small per-batch [66,92)
  u16* cat1b  = (u16*)(ws + 18 * MB);
  u16* qb     = (u16*)(ws + 34 * MB);
  u16* kvb    = (u16*)(ws + 50 * MB);
  u16* obf    = (u16*)(ws + 82 * MB);
  u16* yb     = (u16*)(ws + 34 * MB);
  u16* fbuf   = (u16*)(ws + 66 * MB);
  float* outp = (float*)d_out;
  const bool big = ws_size >= 168 * MB;

  dim3 blk256(256);
  dim3 blk512(512);
  convert_all<<<total_blocks, 256, 0, stream>>>(ca, arena);

  gemm1x1_ln<128, 128><<<dim3(HW_ / 64, 4), blk256, 0, stream>>>(
      f1c, f2c, wq, bq, an_g, an_b, 1e-6f, qb);
  gemm1x1_ln<128, 256><<<dim3(HW_ / 64, 4), blk256, 0, stream>>>(
      f2c, f1c, wkv, bkv, anc_g, anc_b, 1e-6f, kvb);
  attn_mfma<<<dim3(64, 4, 4), blk256, 0, stream>>>(qb, kvb, obf);
  fused_proj_ffn<<<dim3(HW_ / 64, 4), blk256, 0, stream>>>(
      obf, wo, bo_, (const float*)d_in[0], (const float*)d_in[1],
      fn_g, fn_b, w_in, b_in, cat1b, yb);
  if (big) {
    dwconv_kernel<<<dim3(16, 256, 4), blk256, 0, stream>>>(yb, w3, b3, w5, b5, w7, b7, fbuf);
    fused_pw_out<<<dim3(HW_ / 64, 4), blk512, 0, stream>>>(
        fbuf, (size_t)768 * HW_, w_pw, b_pw, yb, w_out, b_out, cat1b, outp, 0);
  } else {
    for (int b = 0; b < 4; ++b) {
      dwconv_kernel<<<dim3(16, 256, 1), blk256, 0, stream>>>(
          yb + (size_t)b * 256 * HW_, w3, b3, w5, b5, w7, b7, fbuf);
      fused_pw_out<<<dim3(HW_ / 64, 1), blk512, 0, stream>>>(
          fbuf, 0, w_pw, b_pw, yb, w_out, b_out, cat1b, outp, b);
    }
  }
}